// Round 11
// baseline (124.120 us; speedup 1.0000x reference)
//
#include <hip/hip_runtime.h>
#include <math.h>

#define EPS 1e-5f
#define B 64
#define N 1024
#define W 64
#define R 4
#define NW 1
#define RPB 4   // rows per block in k_link (R6-proven)

typedef float f4 __attribute__((ext_vector_type(4)));

__device__ __forceinline__ float softplus_f(float x) {
    return x > 0.f ? x + log1pf(expf(-x)) : log1pf(expf(x));
}

// Block-wide reduction over 1024 threads (16 waves). sred: 16 floats.
template <bool IS_MAX>
__device__ __forceinline__ float block_reduce(float v, float* sred) {
    #pragma unroll
    for (int off = 32; off >= 1; off >>= 1) {
        float o = __shfl_xor(v, off);
        v = IS_MAX ? fmaxf(v, o) : v + o;
    }
    __syncthreads();                    // protect sred reuse across calls
    if ((threadIdx.x & 63) == 0) sred[threadIdx.x >> 6] = v;
    __syncthreads();
    float r = sred[0];
    #pragma unroll
    for (int i = 1; i < 16; ++i) r = IS_MAX ? fmaxf(r, sred[i]) : r + sred[i];
    return r;
}

// ---- prep1: usage + sharpened cosine acts (one memory pass). grid (4,B)x256
// (verbatim from R10)
__global__ __launch_bounds__(256) void k_prep1(
    const float* __restrict__ memory,
    const float* __restrict__ read_keys,
    const float* __restrict__ read_strengths,
    const float* __restrict__ write_keys,
    const float* __restrict__ write_strengths,
    const float* __restrict__ free_gate,
    const float* __restrict__ prev_read_w,
    const float* __restrict__ prev_write_w,
    const float* __restrict__ prev_usage,
    float* __restrict__ out_usage,
    float* __restrict__ out_rw,    // [B,R,N] sharpened acts (pre-softmax)
    float* __restrict__ out_ww) {  // [B,N]   sharpened acts (pre-softmax)
    __shared__ float sk[5 * W];
    __shared__ float s_knorm[5];
    __shared__ float s_scale[5];
    int b = blockIdx.y;
    int t = threadIdx.x;
    int n = blockIdx.x * 256 + t;

    for (int l = t; l < 5 * W; l += 256) {
        int h = l >> 6, w = l & 63;
        sk[l] = (h < R) ? read_keys[((size_t)b * R + h) * W + w]
                        : write_keys[(size_t)b * W + w];
    }
    __syncthreads();
    if (t < 5) {
        float s = 0.f;
        for (int w = 0; w < W; ++w) s += sk[t * W + w] * sk[t * W + w];
        s_knorm[t] = sqrtf(s + EPS);
        float st = (t < R) ? read_strengths[b * R + t] : write_strengths[b];
        s_scale[t] = softplus_f(st);
    }

    // usage (independent of keys; overlaps the key-norm work)
    float ww = prev_write_w[(size_t)b * N + n];     // NW == 1
    float pun = prev_usage[(size_t)b * N + n];
    float u = pun + (1.f - pun) * ww;
    float phi = 1.f;
    #pragma unroll
    for (int r = 0; r < R; ++r)
        phi *= 1.f - free_gate[b * R + r] * prev_read_w[((size_t)b * R + r) * N + n];
    out_usage[(size_t)b * N + n] = u * phi;

    __syncthreads();

    const f4* mrow = (const f4*)(memory + ((size_t)b * N + n) * W);
    float dot[5] = {0.f, 0.f, 0.f, 0.f, 0.f};
    float msum = 0.f;
    #pragma unroll
    for (int w4 = 0; w4 < W / 4; ++w4) {
        f4 m = mrow[w4];
        msum += m.x * m.x + m.y * m.y + m.z * m.z + m.w * m.w;
        #pragma unroll
        for (int h = 0; h < 5; ++h)
            dot[h] += sk[h * W + w4 * 4 + 0] * m.x + sk[h * W + w4 * 4 + 1] * m.y
                    + sk[h * W + w4 * 4 + 2] * m.z + sk[h * W + w4 * 4 + 3] * m.w;
    }
    float mnorm = sqrtf(msum + EPS);
    #pragma unroll
    for (int h = 0; h < 5; ++h) {
        float sharp = (dot[h] / (s_knorm[h] * mnorm + EPS)) * s_scale[h];
        if (h < R) out_rw[((size_t)b * R + h) * N + n] = sharp;
        else       out_ww[(size_t)b * N + n] = sharp;
    }
}

// ---- alloc (shuffle bitonic) + batched softmax(5) + ww + precedence ----
// (verbatim from R10)
__global__ __launch_bounds__(1024) void k_allocsmww(
    const float* __restrict__ usage,
    float* __restrict__ out_rw,          // acts in, softmax out
    float* __restrict__ out_ww,          // acts in, final ww out
    const float* __restrict__ alloc_gate,
    const float* __restrict__ write_gate,
    const float* __restrict__ prev_prec,
    float* __restrict__ out_prec) {
    __shared__ float snu[N];
    __shared__ int   sid[N];
    __shared__ float pp[N];              // wave partials, then alloc scatter
    __shared__ float sredb[5 * 16];      // batched reduce partials
    __shared__ float sred[16];
    int b = blockIdx.x;
    int t = threadIdx.x;
    int lane = t & 63, wid = t >> 6;

    // ---- issue all global loads early; consumed after the sort ----
    float a[5];
    #pragma unroll
    for (int h = 0; h < R; ++h) a[h] = out_rw[((size_t)b * R + h) * N + t];
    a[4] = out_ww[(size_t)b * N + t];
    float pprec_v = prev_prec[(size_t)b * N + t];
    float ag = alloc_gate[b], wg = write_gate[b];
    float u = EPS + (1.f - EPS) * usage[(size_t)b * N + t];

    // ---- sort: register/shuffle bitonic (desc nu, stable by index) ----
    float nu = 1.f - u;
    int   id = t;
    for (int k = 2; k <= N; k <<= 1) {
        for (int j = k >> 1; j > 0; j >>= 1) {
            bool up = ((t & k) == 0);
            float onu; int oid;
            if (j < 64) {
                onu = __shfl_xor(nu, j);
                oid = __shfl_xor(id, j);
            } else {
                snu[t] = nu; sid[t] = id;
                __syncthreads();
                onu = snu[t ^ j]; oid = sid[t ^ j];
                __syncthreads();
            }
            bool lower = (t & j) == 0;
            float anu = lower ? nu : onu;  int aid = lower ? id : oid;
            float bnu = lower ? onu : nu;  int bid = lower ? oid : id;
            bool a_first = (anu > bnu) || (anu == bnu && aid < bid);
            bool doSwap = up ? !a_first : a_first;
            if (doSwap) { nu = onu; id = oid; }
        }
    }

    // ---- prefix product of sorted usage via wave shuffle-scan ----
    float scan = 1.f - nu;
    #pragma unroll
    for (int d = 1; d < 64; d <<= 1) {
        float v = __shfl_up(scan, d, 64);
        if (lane >= d) scan *= v;
    }
    if (lane == 63) pp[wid] = scan;
    __syncthreads();
    float wpre = 1.f;
    #pragma unroll
    for (int i = 0; i < 16; ++i) {
        float pv = pp[i];
        wpre *= (i < wid) ? pv : 1.f;
    }
    __syncthreads();                     // done reading pp; reuse for scatter
    float sc1 = __shfl_up(scan, 1, 64);
    float excl = (lane == 0) ? wpre : sc1 * wpre;
    pp[id] = nu * excl;                  // scatter sorted_alloc to origin slot
    __syncthreads();
    float alloc_t = pp[t];

    // ---- batched softmax: 5 maxes in one barrier round ----
    float m[5];
    #pragma unroll
    for (int h = 0; h < 5; ++h) {
        float v = a[h];
        #pragma unroll
        for (int off = 32; off >= 1; off >>= 1) v = fmaxf(v, __shfl_xor(v, off));
        if (lane == 0) sredb[h * 16 + wid] = v;
    }
    __syncthreads();
    #pragma unroll
    for (int h = 0; h < 5; ++h) {
        float r = sredb[h * 16];
        #pragma unroll
        for (int i = 1; i < 16; ++i) r = fmaxf(r, sredb[h * 16 + i]);
        m[h] = r;
    }
    __syncthreads();                     // reuse sredb for sums

    // ---- 5 exp-sums in one barrier round ----
    float e[5];
    #pragma unroll
    for (int h = 0; h < 5; ++h) {
        e[h] = expf(a[h] - m[h]);
        float v = e[h];
        #pragma unroll
        for (int off = 32; off >= 1; off >>= 1) v += __shfl_xor(v, off);
        if (lane == 0) sredb[h * 16 + wid] = v;
    }
    __syncthreads();
    float content = 0.f;
    #pragma unroll
    for (int h = 0; h < 5; ++h) {
        float r = sredb[h * 16];
        #pragma unroll
        for (int i = 1; i < 16; ++i) r += sredb[h * 16 + i];
        float p = e[h] / r;
        if (h < R) out_rw[((size_t)b * R + h) * N + t] = p;
        else       content = p;
    }

    // ---- final write weights + precedence ----
    float w = wg * (ag * alloc_t + (1.f - ag) * content);
    float wsum = block_reduce<false>(w, sred);
    out_ww[(size_t)b * N + t] = w;
    out_prec[(size_t)b * N + t] = (1.f - wsum) * pprec_v + w;
}

// ---- link update: RPB=4 rows/block, PLAIN loads/stores (NT removed) ----
__global__ void k_link(const float* __restrict__ ww,
                       const float* __restrict__ pprec,
                       const float* __restrict__ plink,
                       float* __restrict__ link) {
    int row0 = blockIdx.x * RPB;        // 1024 % RPB == 0 -> one batch per block
    int b = row0 >> 10;
    int t = threadIdx.x;                // j-chunk: j in [4t, 4t+4)

    f4 wj = ((const f4*)(ww + (size_t)b * N))[t];
    f4 pj = ((const f4*)(pprec + (size_t)b * N))[t];

    float wi[RPB];
    f4    pl[RPB];
    #pragma unroll
    for (int r = 0; r < RPB; ++r) {
        int row = row0 + r;
        wi[r] = ww[row];
        pl[r] = ((const f4*)plink)[(((size_t)row) << 8) + t];
    }

    #pragma unroll
    for (int r = 0; r < RPB; ++r) {
        int row = row0 + r;
        int i = row & (N - 1);
        f4 a = (1.f - wi[r]) - wj;
        f4 o = a * pl[r] + wi[r] * pj;
        if ((i >> 2) == t) {            // zero the diagonal element
            int jj = i & 3;
            if      (jj == 0) o.x = 0.f;
            else if (jj == 1) o.y = 0.f;
            else if (jj == 2) o.z = 0.f;
            else              o.w = 0.f;
        }
        ((f4*)link)[(((size_t)row) << 8) + t] = o;
    }
}

extern "C" void kernel_launch(void* const* d_in, const int* in_sizes, int n_in,
                              void* d_out, int out_size, void* d_ws, size_t ws_size,
                              hipStream_t stream) {
    const float* memory          = (const float*)d_in[0];
    const float* read_keys       = (const float*)d_in[1];
    const float* read_strengths  = (const float*)d_in[2];
    const float* write_keys      = (const float*)d_in[3];
    const float* write_strengths = (const float*)d_in[4];
    const float* free_gate       = (const float*)d_in[5];
    const float* alloc_gate      = (const float*)d_in[6];
    const float* write_gate      = (const float*)d_in[7];
    const float* prev_read_w     = (const float*)d_in[8];
    const float* prev_write_w    = (const float*)d_in[9];
    const float* prev_usage      = (const float*)d_in[10];
    const float* prev_link       = (const float*)d_in[11];
    const float* prev_prec       = (const float*)d_in[12];

    float* out = (float*)d_out;
    float* out_rw    = out;                               // [B,R,N]
    float* out_ww    = out_rw + (size_t)B * R * N;        // [B,NW,N]
    float* out_usage = out_ww + (size_t)B * NW * N;       // [B,N]
    float* out_link  = out_usage + (size_t)B * N;         // [B,NW,N,N]
    float* out_prec  = out_link + (size_t)B * NW * N * N; // [B,NW,N]

    dim3 g1(N / 256, B);
    k_prep1<<<g1, 256, 0, stream>>>(memory, read_keys, read_strengths,
                                    write_keys, write_strengths, free_gate,
                                    prev_read_w, prev_write_w, prev_usage,
                                    out_usage, out_rw, out_ww);

    k_allocsmww<<<B, 1024, 0, stream>>>(out_usage, out_rw, out_ww,
                                        alloc_gate, write_gate,
                                        prev_prec, out_prec);

    k_link<<<(B * N) / RPB, 256, 0, stream>>>(out_ww, prev_prec,
                                              prev_link, out_link);
}

// Round 12
// 121.777 us; speedup vs baseline: 1.0192x; 1.0192x over previous
//
#include <hip/hip_runtime.h>
#include <math.h>

#define EPS 1e-5f
#define B 64
#define N 1024
#define W 64
#define R 4
#define NW 1
#define RPB 4   // rows per block in k_link (R6-proven)

typedef float f4 __attribute__((ext_vector_type(4)));

__device__ __forceinline__ float softplus_f(float x) {
    return x > 0.f ? x + log1pf(expf(-x)) : log1pf(expf(x));
}

// Block-wide reduction over 1024 threads (16 waves). sred: 16 floats.
template <bool IS_MAX>
__device__ __forceinline__ float block_reduce(float v, float* sred) {
    #pragma unroll
    for (int off = 32; off >= 1; off >>= 1) {
        float o = __shfl_xor(v, off);
        v = IS_MAX ? fmaxf(v, o) : v + o;
    }
    __syncthreads();                    // protect sred reuse across calls
    if ((threadIdx.x & 63) == 0) sred[threadIdx.x >> 6] = v;
    __syncthreads();
    float r = sred[0];
    #pragma unroll
    for (int i = 1; i < 16; ++i) r = IS_MAX ? fmaxf(r, sred[i]) : r + sred[i];
    return r;
}

// ---- prep1: usage + sharpened cosine acts (one memory pass). grid (4,B)x256
// R10 + nontemporal loads on read-once streams.
__global__ __launch_bounds__(256) void k_prep1(
    const float* __restrict__ memory,
    const float* __restrict__ read_keys,
    const float* __restrict__ read_strengths,
    const float* __restrict__ write_keys,
    const float* __restrict__ write_strengths,
    const float* __restrict__ free_gate,
    const float* __restrict__ prev_read_w,
    const float* __restrict__ prev_write_w,
    const float* __restrict__ prev_usage,
    float* __restrict__ out_usage,
    float* __restrict__ out_rw,    // [B,R,N] sharpened acts (pre-softmax)
    float* __restrict__ out_ww) {  // [B,N]   sharpened acts (pre-softmax)
    __shared__ float sk[5 * W];
    __shared__ float s_knorm[5];
    __shared__ float s_scale[5];
    int b = blockIdx.y;
    int t = threadIdx.x;
    int n = blockIdx.x * 256 + t;

    for (int l = t; l < 5 * W; l += 256) {
        int h = l >> 6, w = l & 63;
        sk[l] = (h < R) ? read_keys[((size_t)b * R + h) * W + w]
                        : write_keys[(size_t)b * W + w];
    }
    __syncthreads();
    if (t < 5) {
        float s = 0.f;
        for (int w = 0; w < W; ++w) s += sk[t * W + w] * sk[t * W + w];
        s_knorm[t] = sqrtf(s + EPS);
        float st = (t < R) ? read_strengths[b * R + t] : write_strengths[b];
        s_scale[t] = softplus_f(st);
    }

    // usage (read-once streams -> nontemporal)
    float ww = __builtin_nontemporal_load(prev_write_w + (size_t)b * N + n); // NW==1
    float pun = __builtin_nontemporal_load(prev_usage + (size_t)b * N + n);
    float u = pun + (1.f - pun) * ww;
    float phi = 1.f;
    #pragma unroll
    for (int r = 0; r < R; ++r)
        phi *= 1.f - free_gate[b * R + r] *
               __builtin_nontemporal_load(prev_read_w + ((size_t)b * R + r) * N + n);
    out_usage[(size_t)b * N + n] = u * phi;

    __syncthreads();

    const f4* mrow = (const f4*)(memory + ((size_t)b * N + n) * W);
    float dot[5] = {0.f, 0.f, 0.f, 0.f, 0.f};
    float msum = 0.f;
    #pragma unroll
    for (int w4 = 0; w4 < W / 4; ++w4) {
        f4 m = __builtin_nontemporal_load(mrow + w4);
        msum += m.x * m.x + m.y * m.y + m.z * m.z + m.w * m.w;
        #pragma unroll
        for (int h = 0; h < 5; ++h)
            dot[h] += sk[h * W + w4 * 4 + 0] * m.x + sk[h * W + w4 * 4 + 1] * m.y
                    + sk[h * W + w4 * 4 + 2] * m.z + sk[h * W + w4 * 4 + 3] * m.w;
    }
    float mnorm = sqrtf(msum + EPS);
    #pragma unroll
    for (int h = 0; h < 5; ++h) {
        float sharp = (dot[h] / (s_knorm[h] * mnorm + EPS)) * s_scale[h];
        if (h < R) out_rw[((size_t)b * R + h) * N + n] = sharp;
        else       out_ww[(size_t)b * N + n] = sharp;
    }
}

// ---- alloc (shuffle bitonic) + batched softmax(5) + ww + precedence ----
// (verbatim from R10)
__global__ __launch_bounds__(1024) void k_allocsmww(
    const float* __restrict__ usage,
    float* __restrict__ out_rw,          // acts in, softmax out
    float* __restrict__ out_ww,          // acts in, final ww out
    const float* __restrict__ alloc_gate,
    const float* __restrict__ write_gate,
    const float* __restrict__ prev_prec,
    float* __restrict__ out_prec) {
    __shared__ float snu[N];
    __shared__ int   sid[N];
    __shared__ float pp[N];              // wave partials, then alloc scatter
    __shared__ float sredb[5 * 16];      // batched reduce partials
    __shared__ float sred[16];
    int b = blockIdx.x;
    int t = threadIdx.x;
    int lane = t & 63, wid = t >> 6;

    // ---- issue all global loads early; consumed after the sort ----
    float a[5];
    #pragma unroll
    for (int h = 0; h < R; ++h) a[h] = out_rw[((size_t)b * R + h) * N + t];
    a[4] = out_ww[(size_t)b * N + t];
    float pprec_v = prev_prec[(size_t)b * N + t];
    float ag = alloc_gate[b], wg = write_gate[b];
    float u = EPS + (1.f - EPS) * usage[(size_t)b * N + t];

    // ---- sort: register/shuffle bitonic (desc nu, stable by index) ----
    float nu = 1.f - u;
    int   id = t;
    for (int k = 2; k <= N; k <<= 1) {
        for (int j = k >> 1; j > 0; j >>= 1) {
            bool up = ((t & k) == 0);
            float onu; int oid;
            if (j < 64) {
                onu = __shfl_xor(nu, j);
                oid = __shfl_xor(id, j);
            } else {
                snu[t] = nu; sid[t] = id;
                __syncthreads();
                onu = snu[t ^ j]; oid = sid[t ^ j];
                __syncthreads();
            }
            bool lower = (t & j) == 0;
            float anu = lower ? nu : onu;  int aid = lower ? id : oid;
            float bnu = lower ? onu : nu;  int bid = lower ? oid : id;
            bool a_first = (anu > bnu) || (anu == bnu && aid < bid);
            bool doSwap = up ? !a_first : a_first;
            if (doSwap) { nu = onu; id = oid; }
        }
    }

    // ---- prefix product of sorted usage via wave shuffle-scan ----
    float scan = 1.f - nu;
    #pragma unroll
    for (int d = 1; d < 64; d <<= 1) {
        float v = __shfl_up(scan, d, 64);
        if (lane >= d) scan *= v;
    }
    if (lane == 63) pp[wid] = scan;
    __syncthreads();
    float wpre = 1.f;
    #pragma unroll
    for (int i = 0; i < 16; ++i) {
        float pv = pp[i];
        wpre *= (i < wid) ? pv : 1.f;
    }
    __syncthreads();                     // done reading pp; reuse for scatter
    float sc1 = __shfl_up(scan, 1, 64);
    float excl = (lane == 0) ? wpre : sc1 * wpre;
    pp[id] = nu * excl;                  // scatter sorted_alloc to origin slot
    __syncthreads();
    float alloc_t = pp[t];

    // ---- batched softmax: 5 maxes in one barrier round ----
    float m[5];
    #pragma unroll
    for (int h = 0; h < 5; ++h) {
        float v = a[h];
        #pragma unroll
        for (int off = 32; off >= 1; off >>= 1) v = fmaxf(v, __shfl_xor(v, off));
        if (lane == 0) sredb[h * 16 + wid] = v;
    }
    __syncthreads();
    #pragma unroll
    for (int h = 0; h < 5; ++h) {
        float r = sredb[h * 16];
        #pragma unroll
        for (int i = 1; i < 16; ++i) r = fmaxf(r, sredb[h * 16 + i]);
        m[h] = r;
    }
    __syncthreads();                     // reuse sredb for sums

    // ---- 5 exp-sums in one barrier round ----
    float e[5];
    #pragma unroll
    for (int h = 0; h < 5; ++h) {
        e[h] = expf(a[h] - m[h]);
        float v = e[h];
        #pragma unroll
        for (int off = 32; off >= 1; off >>= 1) v += __shfl_xor(v, off);
        if (lane == 0) sredb[h * 16 + wid] = v;
    }
    __syncthreads();
    float content = 0.f;
    #pragma unroll
    for (int h = 0; h < 5; ++h) {
        float r = sredb[h * 16];
        #pragma unroll
        for (int i = 1; i < 16; ++i) r += sredb[h * 16 + i];
        float p = e[h] / r;
        if (h < R) out_rw[((size_t)b * R + h) * N + t] = p;
        else       content = p;
    }

    // ---- final write weights + precedence ----
    float w = wg * (ag * alloc_t + (1.f - ag) * content);
    float wsum = block_reduce<false>(w, sred);
    out_ww[(size_t)b * N + t] = w;
    out_prec[(size_t)b * N + t] = (1.f - wsum) * pprec_v + w;
}

// ---- link update: RPB=4 rows/block + nontemporal streams (verbatim R10) ----
__global__ void k_link(const float* __restrict__ ww,
                       const float* __restrict__ pprec,
                       const float* __restrict__ plink,
                       float* __restrict__ link) {
    int row0 = blockIdx.x * RPB;        // 1024 % RPB == 0 -> one batch per block
    int b = row0 >> 10;
    int t = threadIdx.x;                // j-chunk: j in [4t, 4t+4)

    f4 wj = ((const f4*)(ww + (size_t)b * N))[t];
    f4 pj = ((const f4*)(pprec + (size_t)b * N))[t];

    float wi[RPB];
    f4    pl[RPB];
    #pragma unroll
    for (int r = 0; r < RPB; ++r) {
        int row = row0 + r;
        wi[r] = ww[row];
        pl[r] = __builtin_nontemporal_load((const f4*)plink + (((size_t)row) << 8) + t);
    }

    #pragma unroll
    for (int r = 0; r < RPB; ++r) {
        int row = row0 + r;
        int i = row & (N - 1);
        f4 a = (1.f - wi[r]) - wj;
        f4 o = a * pl[r] + wi[r] * pj;
        if ((i >> 2) == t) {            // zero the diagonal element
            int jj = i & 3;
            if      (jj == 0) o.x = 0.f;
            else if (jj == 1) o.y = 0.f;
            else if (jj == 2) o.z = 0.f;
            else              o.w = 0.f;
        }
        __builtin_nontemporal_store(o, (f4*)link + (((size_t)row) << 8) + t);
    }
}

extern "C" void kernel_launch(void* const* d_in, const int* in_sizes, int n_in,
                              void* d_out, int out_size, void* d_ws, size_t ws_size,
                              hipStream_t stream) {
    const float* memory          = (const float*)d_in[0];
    const float* read_keys       = (const float*)d_in[1];
    const float* read_strengths  = (const float*)d_in[2];
    const float* write_keys      = (const float*)d_in[3];
    const float* write_strengths = (const float*)d_in[4];
    const float* free_gate       = (const float*)d_in[5];
    const float* alloc_gate      = (const float*)d_in[6];
    const float* write_gate      = (const float*)d_in[7];
    const float* prev_read_w     = (const float*)d_in[8];
    const float* prev_write_w    = (const float*)d_in[9];
    const float* prev_usage      = (const float*)d_in[10];
    const float* prev_link       = (const float*)d_in[11];
    const float* prev_prec       = (const float*)d_in[12];

    float* out = (float*)d_out;
    float* out_rw    = out;                               // [B,R,N]
    float* out_ww    = out_rw + (size_t)B * R * N;        // [B,NW,N]
    float* out_usage = out_ww + (size_t)B * NW * N;       // [B,N]
    float* out_link  = out_usage + (size_t)B * N;         // [B,NW,N,N]
    float* out_prec  = out_link + (size_t)B * NW * N * N; // [B,NW,N]

    dim3 g1(N / 256, B);
    k_prep1<<<g1, 256, 0, stream>>>(memory, read_keys, read_strengths,
                                    write_keys, write_strengths, free_gate,
                                    prev_read_w, prev_write_w, prev_usage,
                                    out_usage, out_rw, out_ww);

    k_allocsmww<<<B, 1024, 0, stream>>>(out_usage, out_rw, out_ww,
                                        alloc_gate, write_gate,
                                        prev_prec, out_prec);

    k_link<<<(B * N) / RPB, 256, 0, stream>>>(out_ww, prev_prec,
                                              prev_link, out_link);
}

// Round 13
// 116.081 us; speedup vs baseline: 1.0693x; 1.0491x over previous
//
#include <hip/hip_runtime.h>
#include <math.h>

#define EPS 1e-5f
#define B 64
#define N 1024
#define W 64
#define R 4
#define NW 1
#define RPB 4   // rows per block in k_link (R6-proven)

typedef float f4 __attribute__((ext_vector_type(4)));

__device__ __forceinline__ float softplus_f(float x) {
    return x > 0.f ? x + log1pf(expf(-x)) : log1pf(expf(x));
}

// Block-wide reduction over 1024 threads (16 waves). sred: 16 floats.
template <bool IS_MAX>
__device__ __forceinline__ float block_reduce(float v, float* sred) {
    #pragma unroll
    for (int off = 32; off >= 1; off >>= 1) {
        float o = __shfl_xor(v, off);
        v = IS_MAX ? fmaxf(v, o) : v + o;
    }
    __syncthreads();                    // protect sred reuse across calls
    if ((threadIdx.x & 63) == 0) sred[threadIdx.x >> 6] = v;
    __syncthreads();
    float r = sred[0];
    #pragma unroll
    for (int i = 1; i < 16; ++i) r = IS_MAX ? fmaxf(r, sred[i]) : r + sred[i];
    return r;
}

// ---- prep1: usage + sharpened cosine acts (one memory pass). grid (4,B)x256
__global__ __launch_bounds__(256) void k_prep1(
    const float* __restrict__ memory,
    const float* __restrict__ read_keys,
    const float* __restrict__ read_strengths,
    const float* __restrict__ write_keys,
    const float* __restrict__ write_strengths,
    const float* __restrict__ free_gate,
    const float* __restrict__ prev_read_w,
    const float* __restrict__ prev_write_w,
    const float* __restrict__ prev_usage,
    float* __restrict__ out_usage,
    float* __restrict__ out_rw,    // [B,R,N] sharpened acts (pre-softmax)
    float* __restrict__ out_ww) {  // [B,N]   sharpened acts (pre-softmax)
    __shared__ float sk[5 * W];
    __shared__ float s_knorm[5];
    __shared__ float s_scale[5];
    int b = blockIdx.y;
    int t = threadIdx.x;
    int n = blockIdx.x * 256 + t;

    for (int l = t; l < 5 * W; l += 256) {
        int h = l >> 6, w = l & 63;
        sk[l] = (h < R) ? read_keys[((size_t)b * R + h) * W + w]
                        : write_keys[(size_t)b * W + w];
    }
    __syncthreads();
    if (t < 5) {
        float s = 0.f;
        for (int w = 0; w < W; ++w) s += sk[t * W + w] * sk[t * W + w];
        s_knorm[t] = sqrtf(s + EPS);
        float st = (t < R) ? read_strengths[b * R + t] : write_strengths[b];
        s_scale[t] = softplus_f(st);
    }

    // usage (independent of keys; overlaps the key-norm work)
    float ww = prev_write_w[(size_t)b * N + n];     // NW == 1
    float pun = prev_usage[(size_t)b * N + n];
    float u = pun + (1.f - pun) * ww;
    float phi = 1.f;
    #pragma unroll
    for (int r = 0; r < R; ++r)
        phi *= 1.f - free_gate[b * R + r] * prev_read_w[((size_t)b * R + r) * N + n];
    out_usage[(size_t)b * N + n] = u * phi;

    __syncthreads();

    const f4* mrow = (const f4*)(memory + ((size_t)b * N + n) * W);
    float dot[5] = {0.f, 0.f, 0.f, 0.f, 0.f};
    float msum = 0.f;
    #pragma unroll
    for (int w4 = 0; w4 < W / 4; ++w4) {
        f4 m = mrow[w4];
        msum += m.x * m.x + m.y * m.y + m.z * m.z + m.w * m.w;
        #pragma unroll
        for (int h = 0; h < 5; ++h)
            dot[h] += sk[h * W + w4 * 4 + 0] * m.x + sk[h * W + w4 * 4 + 1] * m.y
                    + sk[h * W + w4 * 4 + 2] * m.z + sk[h * W + w4 * 4 + 3] * m.w;
    }
    float mnorm = sqrtf(msum + EPS);
    #pragma unroll
    for (int h = 0; h < 5; ++h) {
        float sharp = (dot[h] / (s_knorm[h] * mnorm + EPS)) * s_scale[h];
        if (h < R) out_rw[((size_t)b * R + h) * N + n] = sharp;
        else       out_ww[(size_t)b * N + n] = sharp;
    }
}

// ---- alloc (shuffle bitonic) + batched softmax(5) + ww + precedence ----
__global__ __launch_bounds__(1024) void k_allocsmww(
    const float* __restrict__ usage,
    float* __restrict__ out_rw,          // acts in, softmax out
    float* __restrict__ out_ww,          // acts in, final ww out
    const float* __restrict__ alloc_gate,
    const float* __restrict__ write_gate,
    const float* __restrict__ prev_prec,
    float* __restrict__ out_prec) {
    __shared__ float snu[N];
    __shared__ int   sid[N];
    __shared__ float pp[N];              // wave partials, then alloc scatter
    __shared__ float sredb[5 * 16];      // batched reduce partials
    __shared__ float sred[16];
    int b = blockIdx.x;
    int t = threadIdx.x;
    int lane = t & 63, wid = t >> 6;

    // ---- issue all global loads early; consumed after the sort ----
    float a[5];
    #pragma unroll
    for (int h = 0; h < R; ++h) a[h] = out_rw[((size_t)b * R + h) * N + t];
    a[4] = out_ww[(size_t)b * N + t];
    float pprec_v = prev_prec[(size_t)b * N + t];
    float ag = alloc_gate[b], wg = write_gate[b];
    float u = EPS + (1.f - EPS) * usage[(size_t)b * N + t];

    // ---- sort: register/shuffle bitonic (desc nu, stable by index) ----
    float nu = 1.f - u;
    int   id = t;
    for (int k = 2; k <= N; k <<= 1) {
        for (int j = k >> 1; j > 0; j >>= 1) {
            bool up = ((t & k) == 0);
            float onu; int oid;
            if (j < 64) {
                onu = __shfl_xor(nu, j);
                oid = __shfl_xor(id, j);
            } else {
                snu[t] = nu; sid[t] = id;
                __syncthreads();
                onu = snu[t ^ j]; oid = sid[t ^ j];
                __syncthreads();
            }
            bool lower = (t & j) == 0;
            float anu = lower ? nu : onu;  int aid = lower ? id : oid;
            float bnu = lower ? onu : nu;  int bid = lower ? oid : id;
            bool a_first = (anu > bnu) || (anu == bnu && aid < bid);
            bool doSwap = up ? !a_first : a_first;
            if (doSwap) { nu = onu; id = oid; }
        }
    }

    // ---- prefix product of sorted usage via wave shuffle-scan ----
    float scan = 1.f - nu;
    #pragma unroll
    for (int d = 1; d < 64; d <<= 1) {
        float v = __shfl_up(scan, d, 64);
        if (lane >= d) scan *= v;
    }
    if (lane == 63) pp[wid] = scan;
    __syncthreads();
    float wpre = 1.f;
    #pragma unroll
    for (int i = 0; i < 16; ++i) {
        float pv = pp[i];
        wpre *= (i < wid) ? pv : 1.f;
    }
    __syncthreads();                     // done reading pp; reuse for scatter
    float sc1 = __shfl_up(scan, 1, 64);
    float excl = (lane == 0) ? wpre : sc1 * wpre;
    pp[id] = nu * excl;                  // scatter sorted_alloc to origin slot
    __syncthreads();
    float alloc_t = pp[t];

    // ---- batched softmax: 5 maxes in one barrier round ----
    float m[5];
    #pragma unroll
    for (int h = 0; h < 5; ++h) {
        float v = a[h];
        #pragma unroll
        for (int off = 32; off >= 1; off >>= 1) v = fmaxf(v, __shfl_xor(v, off));
        if (lane == 0) sredb[h * 16 + wid] = v;
    }
    __syncthreads();
    #pragma unroll
    for (int h = 0; h < 5; ++h) {
        float r = sredb[h * 16];
        #pragma unroll
        for (int i = 1; i < 16; ++i) r = fmaxf(r, sredb[h * 16 + i]);
        m[h] = r;
    }
    __syncthreads();                     // reuse sredb for sums

    // ---- 5 exp-sums in one barrier round ----
    float e[5];
    #pragma unroll
    for (int h = 0; h < 5; ++h) {
        e[h] = expf(a[h] - m[h]);
        float v = e[h];
        #pragma unroll
        for (int off = 32; off >= 1; off >>= 1) v += __shfl_xor(v, off);
        if (lane == 0) sredb[h * 16 + wid] = v;
    }
    __syncthreads();
    float content = 0.f;
    #pragma unroll
    for (int h = 0; h < 5; ++h) {
        float r = sredb[h * 16];
        #pragma unroll
        for (int i = 1; i < 16; ++i) r += sredb[h * 16 + i];
        float p = e[h] / r;
        if (h < R) out_rw[((size_t)b * R + h) * N + t] = p;
        else       content = p;
    }

    // ---- final write weights + precedence ----
    float w = wg * (ag * alloc_t + (1.f - ag) * content);
    float wsum = block_reduce<false>(w, sred);
    out_ww[(size_t)b * N + t] = w;
    out_prec[(size_t)b * N + t] = (1.f - wsum) * pprec_v + w;
}

// ---- link update: RPB=4 rows/block + nontemporal streams ----
__global__ void k_link(const float* __restrict__ ww,
                       const float* __restrict__ pprec,
                       const float* __restrict__ plink,
                       float* __restrict__ link) {
    int row0 = blockIdx.x * RPB;        // 1024 % RPB == 0 -> one batch per block
    int b = row0 >> 10;
    int t = threadIdx.x;                // j-chunk: j in [4t, 4t+4)

    f4 wj = ((const f4*)(ww + (size_t)b * N))[t];
    f4 pj = ((const f4*)(pprec + (size_t)b * N))[t];

    float wi[RPB];
    f4    pl[RPB];
    #pragma unroll
    for (int r = 0; r < RPB; ++r) {
        int row = row0 + r;
        wi[r] = ww[row];
        pl[r] = __builtin_nontemporal_load((const f4*)plink + (((size_t)row) << 8) + t);
    }

    #pragma unroll
    for (int r = 0; r < RPB; ++r) {
        int row = row0 + r;
        int i = row & (N - 1);
        f4 a = (1.f - wi[r]) - wj;
        f4 o = a * pl[r] + wi[r] * pj;
        if ((i >> 2) == t) {            // zero the diagonal element
            int jj = i & 3;
            if      (jj == 0) o.x = 0.f;
            else if (jj == 1) o.y = 0.f;
            else if (jj == 2) o.z = 0.f;
            else              o.w = 0.f;
        }
        __builtin_nontemporal_store(o, (f4*)link + (((size_t)row) << 8) + t);
    }
}

extern "C" void kernel_launch(void* const* d_in, const int* in_sizes, int n_in,
                              void* d_out, int out_size, void* d_ws, size_t ws_size,
                              hipStream_t stream) {
    const float* memory          = (const float*)d_in[0];
    const float* read_keys       = (const float*)d_in[1];
    const float* read_strengths  = (const float*)d_in[2];
    const float* write_keys      = (const float*)d_in[3];
    const float* write_strengths = (const float*)d_in[4];
    const float* free_gate       = (const float*)d_in[5];
    const float* alloc_gate      = (const float*)d_in[6];
    const float* write_gate      = (const float*)d_in[7];
    const float* prev_read_w     = (const float*)d_in[8];
    const float* prev_write_w    = (const float*)d_in[9];
    const float* prev_usage      = (const float*)d_in[10];
    const float* prev_link       = (const float*)d_in[11];
    const float* prev_prec       = (const float*)d_in[12];

    float* out = (float*)d_out;
    float* out_rw    = out;                               // [B,R,N]
    float* out_ww    = out_rw + (size_t)B * R * N;        // [B,NW,N]
    float* out_usage = out_ww + (size_t)B * NW * N;       // [B,N]
    float* out_link  = out_usage + (size_t)B * N;         // [B,NW,N,N]
    float* out_prec  = out_link + (size_t)B * NW * N * N; // [B,NW,N]

    dim3 g1(N / 256, B);
    k_prep1<<<g1, 256, 0, stream>>>(memory, read_keys, read_strengths,
                                    write_keys, write_strengths, free_gate,
                                    prev_read_w, prev_write_w, prev_usage,
                                    out_usage, out_rw, out_ww);

    k_allocsmww<<<B, 1024, 0, stream>>>(out_usage, out_rw, out_ww,
                                        alloc_gate, write_gate,
                                        prev_prec, out_prec);

    k_link<<<(B * N) / RPB, 256, 0, stream>>>(out_ww, prev_prec,
                                              prev_link, out_link);
}